// Round 2
// baseline (559.738 us; speedup 1.0000x reference)
//
#include <hip/hip_runtime.h>
#include <cstdint>
#include <cstddef>

typedef float v4f __attribute__((ext_vector_type(4)));
typedef short short8 __attribute__((ext_vector_type(8)));

constexpr int B_ = 8, P_ = 16384, Q_ = 256, E_ = 128;

// ---------- helpers ----------
__device__ __forceinline__ unsigned int f2bf(float f) {
  unsigned int x = __float_as_uint(f);
  x += 0x7FFFu + ((x >> 16) & 1u);           // round-to-nearest-even
  return x >> 16;
}
__device__ __forceinline__ float softplus_f(float x) {
  return fmaxf(x, 0.f) + __logf(1.f + __expf(-fabsf(x)));
}
__device__ __forceinline__ short8 mk8(unsigned a, unsigned b, unsigned c, unsigned d) {
  union { unsigned u[4]; short8 s; } x;
  x.u[0] = a; x.u[1] = b; x.u[2] = c; x.u[3] = d; return x.s;
}
__device__ __forceinline__ float wsum(float v) {
#pragma unroll
  for (int o = 32; o; o >>= 1) v += __shfl_xor(v, o, 64);
  return v;
}
// LDS-only barrier (no vmcnt drain): global prefetch loads target registers,
// so only LDS traffic needs ordering across waves.
__device__ __forceinline__ void lds_barrier() {
  asm volatile("s_waitcnt lgkmcnt(0)" ::: "memory");
  __builtin_amdgcn_s_barrier();
}

// ---------- fused: prep + both GEMMs ----------
// grid = 8b x 32ks = 256 blocks x 512 threads, 1 block/CU (reg-capped:
// 128 arch VGPR + 128 AGPR acc = 256 unified -> 2 waves/SIMD).
// R1 lesson: consume-all-at-top prefetch + 2-barrier lockstep serialize the
// iteration (12.3us vs ~4us of real work). This version:
//  - row-pair streamed loads: consume 4 -> reissue 4 -> compute, FIFO order,
//    so the compiler emits counted vmcnt and memory streams instead of bursts
//  - double-buffered LDS tile (2 x 50176B), ONE lds_barrier per iteration:
//    wave skew overlaps VALU(compute) with LDS(frag reads) and MFMA
//  - split-K partials stored directly (no 16.8M-atomic tail) when ws allows
template<bool DIRECT>
__global__ __launch_bounds__(512, 2) void fused_all(
    const float* __restrict__ mlv, const int* __restrict__ mask,
    const float* __restrict__ seg, float* __restrict__ part,
    float* __restrict__ negsum, float* __restrict__ ppsum,
    float* __restrict__ segsum, float* __restrict__ nnzb)
{
  __shared__ __align__(16) unsigned int lds[25088];   // 2 x 50176 B
  const int t = threadIdx.x, w = t >> 6, l = t & 63;
  const int lm = l & 15, quad = l >> 4;
  const int wr = w & 3, wc = w >> 2;
  const int jj = l >> 5, le = l & 31;
  const int b = blockIdx.x >> 5, ks = blockIdx.x & 31;

  v4f acc0[4][4], acc1[4][4];
#pragma unroll
  for (int i = 0; i < 4; ++i)
#pragma unroll
    for (int j = 0; j < 4; ++j) { acc0[i][j] = (v4f)0.f; acc1[i][j] = (v4f)0.f; }
  float accN[4] = {0.f,0.f,0.f,0.f};
  float accP[4] = {0.f,0.f,0.f,0.f};
  float accS[4] = {0.f,0.f,0.f,0.f};
  float cnt = 0.f;

  const float* mp = mlv + ((size_t)b * P_ + ks * 512 + 4 * w) * Q_ + 4 * l;
  const int*   kp = mask + ((size_t)b * P_ + ks * 512 + 4 * w) * Q_ + 4 * l;
  const float* sp = seg + ((size_t)b * P_ + ks * 512 + 4 * w + 2 * jj) * E_ + 4 * le;

  // initial loads, FIFO order matching per-iteration consume order
  float4 X[4]; int4 M[4]; float4 S0, S1;
  X[0] = *(const float4*)(mp);           M[0] = *(const int4*)(kp);
  X[1] = *(const float4*)(mp + Q_);      M[1] = *(const int4*)(kp + Q_);
  X[2] = *(const float4*)(mp + 2 * Q_);  M[2] = *(const int4*)(kp + 2 * Q_);
  X[3] = *(const float4*)(mp + 3 * Q_);  M[3] = *(const int4*)(kp + 3 * Q_);
  S0 = *(const float4*)(sp);             S1 = *(const float4*)(sp + E_);

#pragma unroll 2
  for (int it = 0; it < 16; ++it) {
    unsigned int* L  = lds + (it & 1) * 12544;
    unsigned int* A1 = L;
    unsigned int* EZ = L + 4160;
    unsigned int* SB = L + 8320;
    unsigned int* ST = L + 10432;
    const float* mp2 = mp + 32 * Q_;
    const int*   kp2 = kp + 32 * Q_;
    const float* sp2 = sp + 32 * E_;
    const bool pf = (it < 15);

    // ---------- pair A: p-rows 4w+0, 4w+1 -> LDS k-row 2w ----------
    {
      float xs0[4] = {X[0].x, X[0].y, X[0].z, X[0].w};
      int   ms0[4] = {M[0].x, M[0].y, M[0].z, M[0].w};
      float xs1[4] = {X[1].x, X[1].y, X[1].z, X[1].w};
      int   ms1[4] = {M[1].x, M[1].y, M[1].z, M[1].w};
      if (pf) {                                   // reissue 4 (oldest slots)
        X[0] = *(const float4*)(mp2);       M[0] = *(const int4*)(kp2);
        X[1] = *(const float4*)(mp2 + Q_);  M[1] = *(const int4*)(kp2 + Q_);
      }
      float ez0[4], ez1[4], s0 = 0.f, s1 = 0.f;
#pragma unroll
      for (int j = 0; j < 4; ++j) {
        const float e0 = ms0[j] ? __expf(xs0[j]) : 0.f;
        const float e1 = ms1[j] ? __expf(xs1[j]) : 0.f;
        ez0[j] = e0; ez1[j] = e1; s0 += e0; s1 += e1;
        accN[j] += __logf(1.f + e0) + __logf(1.f + e1);
      }
      s0 = wsum(s0); s1 = wsum(s1);
      const float i0 = (s0 > 0.f) ? 1.f / s0 : 0.f;
      const float i1 = (s1 > 0.f) ? 1.f / s1 : 0.f;
      unsigned a_[4], e_[4];
#pragma unroll
      for (int j = 0; j < 4; ++j) {
        a_[j] = f2bf(ms0[j] ? -xs0[j] : 0.f) | (f2bf(ms1[j] ? -xs1[j] : 0.f) << 16);
        const float p0 = ez0[j] * i0, p1 = ez1[j] * i1;
        accP[j] += p0 + p1;
        e_[j] = f2bf(p0) | (f2bf(p1) << 16);
      }
      { uint4 v; v.x=a_[0]; v.y=a_[1]; v.z=a_[2]; v.w=a_[3];
        *(uint4*)(A1 + (2*w) * 260 + 4*l) = v; }
      { uint4 v; v.x=e_[0]; v.y=e_[1]; v.z=e_[2]; v.w=e_[3];
        *(uint4*)(EZ + (2*w) * 260 + 4*l) = v; }
    }

    // ---------- pair B: p-rows 4w+2, 4w+3 -> LDS k-row 2w+1 ----------
    {
      float xs0[4] = {X[2].x, X[2].y, X[2].z, X[2].w};
      int   ms0[4] = {M[2].x, M[2].y, M[2].z, M[2].w};
      float xs1[4] = {X[3].x, X[3].y, X[3].z, X[3].w};
      int   ms1[4] = {M[3].x, M[3].y, M[3].z, M[3].w};
      if (pf) {
        X[2] = *(const float4*)(mp2 + 2 * Q_);  M[2] = *(const int4*)(kp2 + 2 * Q_);
        X[3] = *(const float4*)(mp2 + 3 * Q_);  M[3] = *(const int4*)(kp2 + 3 * Q_);
      }
      float ez0[4], ez1[4], s0 = 0.f, s1 = 0.f;
#pragma unroll
      for (int j = 0; j < 4; ++j) {
        const float e0 = ms0[j] ? __expf(xs0[j]) : 0.f;
        const float e1 = ms1[j] ? __expf(xs1[j]) : 0.f;
        ez0[j] = e0; ez1[j] = e1; s0 += e0; s1 += e1;
        accN[j] += __logf(1.f + e0) + __logf(1.f + e1);
      }
      s0 = wsum(s0); s1 = wsum(s1);
      const float i0 = (s0 > 0.f) ? 1.f / s0 : 0.f;
      const float i1 = (s1 > 0.f) ? 1.f / s1 : 0.f;
      unsigned a_[4], e_[4];
#pragma unroll
      for (int j = 0; j < 4; ++j) {
        a_[j] = f2bf(ms0[j] ? -xs0[j] : 0.f) | (f2bf(ms1[j] ? -xs1[j] : 0.f) << 16);
        const float p0 = ez0[j] * i0, p1 = ez1[j] * i1;
        accP[j] += p0 + p1;
        e_[j] = f2bf(p0) | (f2bf(p1) << 16);
      }
      { uint4 v; v.x=a_[0]; v.y=a_[1]; v.z=a_[2]; v.w=a_[3];
        *(uint4*)(A1 + (2*w + 1) * 260 + 4*l) = v; }
      { uint4 v; v.x=e_[0]; v.y=e_[1]; v.z=e_[2]; v.w=e_[3];
        *(uint4*)(EZ + (2*w + 1) * 260 + 4*l) = v; }
    }

    // ---------- seg step ----------
    {
      float sv0[4] = {S0.x, S0.y, S0.z, S0.w};
      float sv1[4] = {S1.x, S1.y, S1.z, S1.w};
      if (pf) {
        S0 = *(const float4*)(sp2);
        S1 = *(const float4*)(sp2 + E_);
      }
      unsigned sb[4], st_[4];
#pragma unroll
      for (int j = 0; j < 4; ++j) {
        accS[j] += sv0[j] + sv1[j];
        cnt += ((sv0[j] > 0.f) ? 1.f : 0.f) + ((sv1[j] > 0.f) ? 1.f : 0.f);
        sb[j]  = ((sv0[j] > 0.f) ? 0x3F80u : 0u) | ((sv1[j] > 0.f) ? 0x3F800000u : 0u);
        st_[j] = f2bf(sv0[j]) | (f2bf(sv1[j]) << 16);
      }
      { uint4 v; v.x=sb[0]; v.y=sb[1]; v.z=sb[2]; v.w=sb[3];
        *(uint4*)(SB + (2*w + jj) * 132 + 4*le) = v; }
      { uint4 v; v.x=st_[0]; v.y=st_[1]; v.z=st_[2]; v.w=st_[3];
        *(uint4*)(ST + (2*w + jj) * 132 + 4*le) = v; }
    }
    if (pf) { mp = mp2; kp = kp2; sp = sp2; }

    // single barrier per iteration: writes(it)->barrier->reads(it).
    // Double buffer makes the write(it+1) vs read(it-1) hazard safe via
    // barrier(it) alone (write(it+1) is after it; read(it-1) is before it).
    lds_barrier();

    // ---------- MFMA phase: k=32 ----------
    short8 af0[4], af1[4], bf0[4], bf1[4];
#pragma unroll
    for (int i = 0; i < 4; ++i) {
      const int q_abs = wr * 64 + i * 16 + lm;
      const int c0 = 4 * quad;
      af0[i] = mk8(A1[c0*260 + q_abs], A1[(c0+1)*260 + q_abs],
                   A1[(c0+2)*260 + q_abs], A1[(c0+3)*260 + q_abs]);
      af1[i] = mk8(EZ[c0*260 + q_abs], EZ[(c0+1)*260 + q_abs],
                   EZ[(c0+2)*260 + q_abs], EZ[(c0+3)*260 + q_abs]);
    }
#pragma unroll
    for (int j = 0; j < 4; ++j) {
      const int e_abs = wc * 64 + j * 16 + lm;
      const int c0 = 4 * quad;
      bf0[j] = mk8(SB[c0*132 + e_abs], SB[(c0+1)*132 + e_abs],
                   SB[(c0+2)*132 + e_abs], SB[(c0+3)*132 + e_abs]);
      bf1[j] = mk8(ST[c0*132 + e_abs], ST[(c0+1)*132 + e_abs],
                   ST[(c0+2)*132 + e_abs], ST[(c0+3)*132 + e_abs]);
    }
#pragma unroll
    for (int i = 0; i < 4; ++i)
#pragma unroll
      for (int j = 0; j < 4; ++j) {
        acc0[i][j] = __builtin_amdgcn_mfma_f32_16x16x32_bf16(af0[i], bf0[j], acc0[i][j], 0, 0, 0);
        acc1[i][j] = __builtin_amdgcn_mfma_f32_16x16x32_bf16(af1[i], bf1[j], acc1[i][j], 0, 0, 0);
      }
  }

  // ---- small reductions (negsum/ppsum/segsum/nnz) ----
  __syncthreads();
  float* fr = (float*)lds;
#pragma unroll
  for (int j = 0; j < 4; ++j) {
    fr[w * 256 + 4 * l + j] = accN[j];
    fr[2048 + w * 256 + 4 * l + j] = accP[j];
    fr[4096 + (2 * w + jj) * 128 + 4 * le + j] = accS[j];
  }
  __syncthreads();
  if (t < 256) {
    float sn = 0.f, sq = 0.f;
#pragma unroll
    for (int k = 0; k < 8; ++k) { sn += fr[k * 256 + t]; sq += fr[2048 + k * 256 + t]; }
    atomicAdd(&negsum[b * 256 + t], sn);
    atomicAdd(&ppsum[b * 256 + t], sq);
  } else if (t < 384) {
    const int e = t - 256;
    float ss = 0.f;
#pragma unroll
    for (int k = 0; k < 16; ++k) ss += fr[4096 + k * 128 + e];
    atomicAdd(&segsum[b * 128 + e], ss);
  }
  cnt = wsum(cnt);
  if (l == 0) atomicAdd(&nnzb[b], cnt);

  // ---- split-K partials ----
  if constexpr (DIRECT) {
    // plain coalesced stores to this block's private slice; epilogue reduces.
    float* p0 = part + ((size_t)(ks * 8 + b) * 2) * 32768;
    float* p1 = p0 + 32768;
#pragma unroll
    for (int i = 0; i < 4; ++i)
#pragma unroll
      for (int r = 0; r < 4; ++r) {
        const int q = wr * 64 + i * 16 + quad * 4 + r;
#pragma unroll
        for (int j = 0; j < 4; ++j) {
          const int e = wc * 64 + j * 16 + lm;
          p0[q * 128 + e] = acc0[i][j][r];
          p1[q * 128 + e] = acc1[i][j][r];
        }
      }
  } else {
    float* p0 = part + (size_t)b * 32768;
    float* p1 = part + (size_t)(8 + b) * 32768;
#pragma unroll
    for (int i = 0; i < 4; ++i)
#pragma unroll
      for (int r = 0; r < 4; ++r) {
        const int q = wr * 64 + i * 16 + quad * 4 + r;
#pragma unroll
        for (int j = 0; j < 4; ++j) {
          const int e = wc * 64 + j * 16 + lm;
          atomicAdd(&p0[q * 128 + e], acc0[i][j][r]);
          atomicAdd(&p1[q * 128 + e], acc1[i][j][r]);
        }
      }
  }
}

// ---------- epilogue: split-K reduce + all closed-form cost terms ----------
template<bool DIRECT>
__global__ __launch_bounds__(128) void epilogue(
    const float* __restrict__ part,
    const float* __restrict__ negsum, const float* __restrict__ ppsum,
    const float* __restrict__ segsum, const float* __restrict__ nnzb,
    const float* __restrict__ logits, const float* __restrict__ ppos,
    const float* __restrict__ chol, const float* __restrict__ tpos,
    const float* __restrict__ imgsz, float* __restrict__ out)
{
  const int bq = blockIdx.x;          // b*256 + q
  const int b = bq >> 8;
  const int e = threadIdx.x;
  const int qe = (bq & 255) * 128 + e;

  float g1, g2;
  if constexpr (DIRECT) {
    g1 = 0.f; g2 = 0.f;
#pragma unroll 8
    for (int ksi = 0; ksi < 32; ++ksi) {
      g1 += part[((size_t)(ksi * 8 + b) * 2) * 32768 + qe];
      g2 += part[((size_t)(ksi * 8 + b) * 2 + 1) * 32768 + qe];
    }
  } else {
    g1 = part[(size_t)b * 32768 + qe];
    g2 = part[(size_t)(8 + b) * 32768 + qe];
  }

  const float nnz = fmaxf(nnzb[b], 1.f);
  const float mask_cost = (negsum[bq] + g1) / nnz;
  const float dice = 1.f - (2.f * g2 + 1.f) / (ppsum[bq] + segsum[b * 128 + e] + 1.f);
  const float cls = softplus_f(-logits[bq]);
  const float px = ppos[bq * 2], py = ppos[bq * 2 + 1];
  const float tx = tpos[(b * 128 + e) * 2], ty = tpos[(b * 128 + e) * 2 + 1];
  const float dx = px - tx, dy = py - ty;
  const float ax = fabsf(dx), ay = fabsf(dy);
  const float hx = (ax < 1.f) ? 0.5f * dx * dx : ax - 0.5f;
  const float hy = (ay < 1.f) ? 0.5f * dy * dy : ay - 0.5f;
  const float huber = 0.5f * (hx + hy);
  const float sx = imgsz[b * 2], sy = imgsz[b * 2 + 1];
  const float L00 = chol[bq * 4 + 0], L10 = chol[bq * 4 + 2], L11 = chol[bq * 4 + 3];
  const float d0 = (tx - px) * sx, d1 = (ty - py) * sy;
  const float z0 = d0 / L00;
  const float z1 = (d1 - L10 * z0) / L11;
  const float nll = 0.5f * (z0 * z0 + z1 * z1) + 1.8378770664093453f + __logf(L00) + __logf(L11);
  const float lik = 1.f - __expf(-nll);
  out[bq * 128 + e] = 2.f * cls + 5.f * mask_cost + 5.f * dice + huber + 0.5f * nll + 0.5f * lik;
}

// ---------- launcher ----------
extern "C" void kernel_launch(void* const* d_in, const int* in_sizes, int n_in,
                              void* d_out, int out_size, void* d_ws, size_t ws_size,
                              hipStream_t stream)
{
  (void)in_sizes; (void)n_in; (void)out_size;
  const float* logits = (const float*)d_in[0];
  const float* mlv    = (const float*)d_in[1];
  const int*   mask   = (const int*)d_in[2];
  const float* seg    = (const float*)d_in[3];
  const float* ppos   = (const float*)d_in[4];
  const float* chol   = (const float*)d_in[5];
  const float* tpos   = (const float*)d_in[6];
  const float* imgsz  = (const float*)d_in[7];

  char* ws = (char*)d_ws;
  const size_t PART_DIRECT = 67108864ull;               // 32ks*8b*2g*32768*4B
  const size_t NEED = PART_DIRECT + 20512ull;

  if (ws_size >= NEED) {
    float* part   = (float*)ws;
    float* negsum = (float*)(ws + PART_DIRECT);
    float* ppsum  = (float*)(ws + PART_DIRECT + 8192);
    float* segsum = (float*)(ws + PART_DIRECT + 16384);
    float* nnzb   = (float*)(ws + PART_DIRECT + 20480);
    hipMemsetAsync(ws + PART_DIRECT, 0, 20512, stream);  // only the small sums
    fused_all<true><<<256, 512, 0, stream>>>(mlv, mask, seg, part, negsum, ppsum, segsum, nnzb);
    epilogue<true><<<2048, 128, 0, stream>>>(part, negsum, ppsum, segsum, nnzb,
                                             logits, ppos, chol, tpos, imgsz, (float*)d_out);
  } else {
    float* part   = (float*)(ws);                    // [2][8][256][128]
    float* negsum = (float*)(ws + 2097152);
    float* ppsum  = (float*)(ws + 2105344);
    float* segsum = (float*)(ws + 2113536);
    float* nnzb   = (float*)(ws + 2117632);
    hipMemsetAsync(ws, 0, 2117664, stream);
    fused_all<false><<<256, 512, 0, stream>>>(mlv, mask, seg, part, negsum, ppsum, segsum, nnzb);
    epilogue<false><<<2048, 128, 0, stream>>>(part, negsum, ppsum, segsum, nnzb,
                                              logits, ppos, chol, tpos, imgsz, (float*)d_out);
  }
}

// Round 5
// 421.034 us; speedup vs baseline: 1.3294x; 1.3294x over previous
//
#include <hip/hip_runtime.h>
#include <cstdint>
#include <cstddef>

typedef float v4f __attribute__((ext_vector_type(4)));
typedef short short8 __attribute__((ext_vector_type(8)));

constexpr int B_ = 8, P_ = 16384, Q_ = 256, E_ = 128;

// ---------- helpers ----------
__device__ __forceinline__ unsigned int f2bf(float f) {
  unsigned int x = __float_as_uint(f);
  x += 0x7FFFu + ((x >> 16) & 1u);           // round-to-nearest-even
  return x >> 16;
}
__device__ __forceinline__ float softplus_f(float x) {
  return fmaxf(x, 0.f) + __logf(1.f + __expf(-fabsf(x)));
}
__device__ __forceinline__ float wsum(float v) {
#pragma unroll
  for (int o = 32; o; o >>= 1) v += __shfl_xor(v, o, 64);
  return v;
}
// LDS-only barrier (no vmcnt drain); proven correct in R1.
__device__ __forceinline__ void lds_barrier() {
  asm volatile("s_waitcnt lgkmcnt(0)" ::: "memory");
  __builtin_amdgcn_s_barrier();
}
// q-major LDS word address with 3-bit XOR swizzle (word bits 2-4 ^= q bits 3-5).
// Bijective (each bit XORed with strictly-higher bits). Keeps 16B read blocks
// and 8B write pairs contiguous (word bits 0-1 untouched).
__device__ __forceinline__ int swz(int q, int kp) {
  return ((q << 4) | kp) ^ (((q >> 3) & 7) << 2);
}

// ---------- fused: prep + both GEMMs, split-K ----------
// grid = 8b x 32ks = 256 blocks x 512 threads, 1 block/CU (256 unified regs:
// 128 arch + 128 AGPR acc -> 2 waves/SIMD; R2 proved any extra state spills).
// R1 skeleton: consume-all-at-top prefetch, single LDS buffer, 2 lds_barriers.
// R3/R4 changes:
//  - q-major swizzled LDS tiles: frag read = ONE ds_read_b128 (was 4x b32 + mk8
//    VALU packing). Reads conflict-free by construction; writes 8-way b64 /
//    4-way b32 (cheap, m136).
//  - split-K partials stored to private slices (no 16.8M-atomic near-memory
//    RMW tail; R0/R1 WRITE_SIZE=112MB evidence); epilogue reduces 32 slices.
template<bool DIRECT>
__global__ __launch_bounds__(512, 2) void fused_all(
    const float* __restrict__ mlv, const int* __restrict__ mask,
    const float* __restrict__ seg, float* __restrict__ part,
    float* __restrict__ negsum, float* __restrict__ ppsum,
    float* __restrict__ segsum, float* __restrict__ nnzb)
{
  __shared__ __align__(16) unsigned int lds[12288];   // 49152 B
  unsigned int* A1q = lds;            // 256q x 16 words
  unsigned int* EZq = lds + 4096;     // 256q x 16
  unsigned int* SBq = lds + 8192;     // 128e x 16
  unsigned int* STq = lds + 10240;    // 128e x 16

  const int t = threadIdx.x, w = t >> 6, l = t & 63;
  const int lm = l & 15, quad = l >> 4;
  const int wr = w & 3, wc = w >> 2;
  const int jj = l >> 5, le = l & 31;
  const int b = blockIdx.x >> 5, ks = blockIdx.x & 31;

  v4f acc0[4][4], acc1[4][4];
#pragma unroll
  for (int i = 0; i < 4; ++i)
#pragma unroll
    for (int j = 0; j < 4; ++j) { acc0[i][j] = (v4f)0.f; acc1[i][j] = (v4f)0.f; }
  float accN[4] = {0.f,0.f,0.f,0.f};
  float accP[4] = {0.f,0.f,0.f,0.f};
  float accS[4] = {0.f,0.f,0.f,0.f};
  float cnt = 0.f;

  const float* mp = mlv + ((size_t)b * P_ + ks * 512 + 4 * w) * Q_ + 4 * l;
  const int*   kp = mask + ((size_t)b * P_ + ks * 512 + 4 * w) * Q_ + 4 * l;
  const float* sp = seg + ((size_t)b * P_ + ks * 512 + 4 * w + 2 * jj) * E_ + 4 * le;

  float4 X[4]; int4 M[4]; float4 S0, S1;
#pragma unroll
  for (int r = 0; r < 4; ++r) {
    X[r] = *(const float4*)(mp + (size_t)r * Q_);
    M[r] = *(const int4*)(kp + (size_t)r * Q_);
  }
  S0 = *(const float4*)(sp);
  S1 = *(const float4*)(sp + E_);

  for (int it = 0; it < 16; ++it) {
    // ---- unpack & compute ----
    float xs[4][4]; int ms[4][4];
#pragma unroll
    for (int r = 0; r < 4; ++r) {
      xs[r][0] = X[r].x; xs[r][1] = X[r].y; xs[r][2] = X[r].z; xs[r][3] = X[r].w;
      ms[r][0] = M[r].x; ms[r][1] = M[r].y; ms[r][2] = M[r].z; ms[r][3] = M[r].w;
    }
    float sv0[4] = {S0.x, S0.y, S0.z, S0.w};
    float sv1[4] = {S1.x, S1.y, S1.z, S1.w};

    // ---- prefetch next step (issues early, completes during this iter) ----
    if (it < 15) {
      mp += 32 * Q_; kp += 32 * Q_; sp += 32 * E_;
#pragma unroll
      for (int r = 0; r < 4; ++r) {
        X[r] = *(const float4*)(mp + (size_t)r * Q_);
        M[r] = *(const int4*)(kp + (size_t)r * Q_);
      }
      S0 = *(const float4*)(sp);
      S1 = *(const float4*)(sp + E_);
    }

    float ez[4][4], rs[4];
#pragma unroll
    for (int r = 0; r < 4; ++r) {
      float s = 0.f;
#pragma unroll
      for (int j = 0; j < 4; ++j) {
        const bool mm = ms[r][j] != 0;
        const float e = mm ? __expf(xs[r][j]) : 0.f;
        ez[r][j] = e; s += e;
        accN[j] += __logf(1.f + e);                    // softplus(x) on masked
      }
      rs[r] = s;
    }
#pragma unroll
    for (int r = 0; r < 4; ++r) rs[r] = wsum(rs[r]);
    float inv[4];
#pragma unroll
    for (int r = 0; r < 4; ++r) inv[r] = (rs[r] > 0.f) ? (1.f / rs[r]) : 0.f;

    unsigned int a1p[2][4], ezp[2][4];
#pragma unroll
    for (int jp = 0; jp < 2; ++jp)
#pragma unroll
      for (int j = 0; j < 4; ++j) {
        const int r0 = 2 * jp, r1 = 2 * jp + 1;
        a1p[jp][j] = f2bf(ms[r0][j] ? -xs[r0][j] : 0.f)
                   | (f2bf(ms[r1][j] ? -xs[r1][j] : 0.f) << 16);
        const float p0 = ez[r0][j] * inv[r0];
        const float p1 = ez[r1][j] * inv[r1];
        accP[j] += p0 + p1;
        ezp[jp][j] = f2bf(p0) | (f2bf(p1) << 16);
      }
    unsigned int sb[4], st_[4];
#pragma unroll
    for (int j = 0; j < 4; ++j) {
      accS[j] += sv0[j] + sv1[j];
      cnt += ((sv0[j] > 0.f) ? 1.f : 0.f) + ((sv1[j] > 0.f) ? 1.f : 0.f);
      sb[j]  = ((sv0[j] > 0.f) ? 0x3F80u : 0u) | ((sv1[j] > 0.f) ? 0x3F800000u : 0u);
      st_[j] = f2bf(sv0[j]) | (f2bf(sv1[j]) << 16);
    }

    lds_barrier();   // previous MFMA phase done reading LDS
    // A/EZ: thread owns q = 4l..4l+3, kp pair {2w, 2w+1} -> uint2 (b64) each.
    //   word(q, kp=2w) .x = rows (4w+0,4w+1), .y = rows (4w+2,4w+3).
#pragma unroll
    for (int j = 0; j < 4; ++j) {
      const int q = 4 * l + j;
      const int wa = swz(q, 2 * w);
      uint2 va; va.x = a1p[0][j]; va.y = a1p[1][j];
      uint2 ve; ve.x = ezp[0][j]; ve.y = ezp[1][j];
      *(uint2*)(A1q + wa) = va;
      *(uint2*)(EZq + wa) = ve;
    }
    // SB/ST: thread owns e = 4le..4le+3, single word kp = 2w+jj.
#pragma unroll
    for (int j = 0; j < 4; ++j) {
      const int e = 4 * le + j;
      const int wb = swz(e, 2 * w + jj);
      SBq[wb] = sb[j];
      STq[wb] = st_[j];
    }
    lds_barrier();   // writes visible to all waves

    // ---- MFMA phase: k=32, one ds_read_b128 per fragment ----
    short8 af0[4], af1[4], bf0[4], bf1[4];
#pragma unroll
    for (int i = 0; i < 4; ++i) {
      const int q_abs = wr * 64 + i * 16 + lm;
      const int wa = swz(q_abs, 4 * quad);
      af0[i] = *(const short8*)(A1q + wa);
      af1[i] = *(const short8*)(EZq + wa);
    }
#pragma unroll
    for (int j = 0; j < 4; ++j) {
      const int e_abs = wc * 64 + j * 16 + lm;
      const int wb = swz(e_abs, 4 * quad);
      bf0[j] = *(const short8*)(SBq + wb);
      bf1[j] = *(const short8*)(STq + wb);
    }
#pragma unroll
    for (int i = 0; i < 4; ++i)
#pragma unroll
      for (int j = 0; j < 4; ++j) {
        acc0[i][j] = __builtin_amdgcn_mfma_f32_16x16x32_bf16(af0[i], bf0[j], acc0[i][j], 0, 0, 0);
        acc1[i][j] = __builtin_amdgcn_mfma_f32_16x16x32_bf16(af1[i], bf1[j], acc1[i][j], 0, 0, 0);
      }
  }

  // ---- small reductions (negsum/ppsum/segsum/nnz) ----
  __syncthreads();
  float* fr = (float*)lds;
#pragma unroll
  for (int j = 0; j < 4; ++j) {
    fr[w * 256 + 4 * l + j] = accN[j];
    fr[2048 + w * 256 + 4 * l + j] = accP[j];
    fr[4096 + (2 * w + jj) * 128 + 4 * le + j] = accS[j];
  }
  __syncthreads();
  if (t < 256) {
    float sn = 0.f, sq = 0.f;
#pragma unroll
    for (int k = 0; k < 8; ++k) { sn += fr[k * 256 + t]; sq += fr[2048 + k * 256 + t]; }
    atomicAdd(&negsum[b * 256 + t], sn);
    atomicAdd(&ppsum[b * 256 + t], sq);
  } else if (t < 384) {
    const int e = t - 256;
    float ss = 0.f;
#pragma unroll
    for (int k = 0; k < 16; ++k) ss += fr[4096 + k * 128 + e];
    atomicAdd(&segsum[b * 128 + e], ss);
  }
  cnt = wsum(cnt);
  if (l == 0) atomicAdd(&nnzb[b], cnt);

  // ---- split-K partials ----
  if constexpr (DIRECT) {
    // private per-block slices, plain coalesced stores; epilogue reduces.
    float* p0 = part + ((size_t)(ks * 8 + b) * 2) * 32768;
    float* p1 = p0 + 32768;
#pragma unroll
    for (int i = 0; i < 4; ++i)
#pragma unroll
      for (int r = 0; r < 4; ++r) {
        const int q = wr * 64 + i * 16 + quad * 4 + r;
#pragma unroll
        for (int j = 0; j < 4; ++j) {
          const int e = wc * 64 + j * 16 + lm;
          p0[q * 128 + e] = acc0[i][j][r];
          p1[q * 128 + e] = acc1[i][j][r];
        }
      }
  } else {
    float* p0 = part + (size_t)b * 32768;
    float* p1 = part + (size_t)(8 + b) * 32768;
#pragma unroll
    for (int i = 0; i < 4; ++i)
#pragma unroll
      for (int r = 0; r < 4; ++r) {
        const int q = wr * 64 + i * 16 + quad * 4 + r;
#pragma unroll
        for (int j = 0; j < 4; ++j) {
          const int e = wc * 64 + j * 16 + lm;
          atomicAdd(&p0[q * 128 + e], acc0[i][j][r]);
          atomicAdd(&p1[q * 128 + e], acc1[i][j][r]);
        }
      }
  }
}

// ---------- epilogue: split-K reduce + all closed-form cost terms ----------
template<bool DIRECT>
__global__ __launch_bounds__(128) void epilogue(
    const float* __restrict__ part,
    const float* __restrict__ negsum, const float* __restrict__ ppsum,
    const float* __restrict__ segsum, const float* __restrict__ nnzb,
    const float* __restrict__ logits, const float* __restrict__ ppos,
    const float* __restrict__ chol, const float* __restrict__ tpos,
    const float* __restrict__ imgsz, float* __restrict__ out)
{
  const int bq = blockIdx.x;          // b*256 + q
  const int b = bq >> 8;
  const int e = threadIdx.x;
  const int qe = (bq & 255) * 128 + e;

  float g1, g2;
  if constexpr (DIRECT) {
    g1 = 0.f; g2 = 0.f;
#pragma unroll 8
    for (int ksi = 0; ksi < 32; ++ksi) {
      g1 += part[((size_t)(ksi * 8 + b) * 2) * 32768 + qe];
      g2 += part[((size_t)(ksi * 8 + b) * 2 + 1) * 32768 + qe];
    }
  } else {
    g1 = part[(size_t)b * 32768 + qe];
    g2 = part[(size_t)(8 + b) * 32768 + qe];
  }

  const float nnz = fmaxf(nnzb[b], 1.f);
  const float mask_cost = (negsum[bq] + g1) / nnz;
  const float dice = 1.f - (2.f * g2 + 1.f) / (ppsum[bq] + segsum[b * 128 + e] + 1.f);
  const float cls = softplus_f(-logits[bq]);
  const float px = ppos[bq * 2], py = ppos[bq * 2 + 1];
  const float tx = tpos[(b * 128 + e) * 2], ty = tpos[(b * 128 + e) * 2 + 1];
  const float dx = px - tx, dy = py - ty;
  const float ax = fabsf(dx), ay = fabsf(dy);
  const float hx = (ax < 1.f) ? 0.5f * dx * dx : ax - 0.5f;
  const float hy = (ay < 1.f) ? 0.5f * dy * dy : ay - 0.5f;
  const float huber = 0.5f * (hx + hy);
  const float sx = imgsz[b * 2], sy = imgsz[b * 2 + 1];
  const float L00 = chol[bq * 4 + 0], L10 = chol[bq * 4 + 2], L11 = chol[bq * 4 + 3];
  const float d0 = (tx - px) * sx, d1 = (ty - py) * sy;
  const float z0 = d0 / L00;
  const float z1 = (d1 - L10 * z0) / L11;
  const float nll = 0.5f * (z0 * z0 + z1 * z1) + 1.8378770664093453f + __logf(L00) + __logf(L11);
  const float lik = 1.f - __expf(-nll);
  out[bq * 128 + e] = 2.f * cls + 5.f * mask_cost + 5.f * dice + huber + 0.5f * nll + 0.5f * lik;
}

// ---------- launcher ----------
extern "C" void kernel_launch(void* const* d_in, const int* in_sizes, int n_in,
                              void* d_out, int out_size, void* d_ws, size_t ws_size,
                              hipStream_t stream)
{
  (void)in_sizes; (void)n_in; (void)out_size;
  const float* logits = (const float*)d_in[0];
  const float* mlv    = (const float*)d_in[1];
  const int*   mask   = (const int*)d_in[2];
  const float* seg    = (const float*)d_in[3];
  const float* ppos   = (const float*)d_in[4];
  const float* chol   = (const float*)d_in[5];
  const float* tpos   = (const float*)d_in[6];
  const float* imgsz  = (const float*)d_in[7];

  char* ws = (char*)d_ws;
  const size_t PART_DIRECT = 67108864ull;               // 32ks*8b*2g*32768*4B
  const size_t NEED = PART_DIRECT + 20512ull;

  if (ws_size >= NEED) {
    float* part   = (float*)ws;
    float* negsum = (float*)(ws + PART_DIRECT);
    float* ppsum  = (float*)(ws + PART_DIRECT + 8192);
    float* segsum = (float*)(ws + PART_DIRECT + 16384);
    float* nnzb   = (float*)(ws + PART_DIRECT + 20480);
    hipMemsetAsync(ws + PART_DIRECT, 0, 20512, stream);  // only the small sums
    fused_all<true><<<256, 512, 0, stream>>>(mlv, mask, seg, part, negsum, ppsum, segsum, nnzb);
    epilogue<true><<<2048, 128, 0, stream>>>(part, negsum, ppsum, segsum, nnzb,
                                             logits, ppos, chol, tpos, imgsz, (float*)d_out);
  } else {
    float* part   = (float*)(ws);                    // [2][8][256][128]
    float* negsum = (float*)(ws + 2097152);
    float* ppsum  = (float*)(ws + 2105344);
    float* segsum = (float*)(ws + 2113536);
    float* nnzb   = (float*)(ws + 2117632);
    hipMemsetAsync(ws, 0, 2117664, stream);
    fused_all<false><<<256, 512, 0, stream>>>(mlv, mask, seg, part, negsum, ppsum, segsum, nnzb);
    epilogue<false><<<2048, 128, 0, stream>>>(part, negsum, ppsum, segsum, nnzb,
                                              logits, ppos, chol, tpos, imgsz, (float*)d_out);
  }
}